// Round 6
// baseline (594.668 us; speedup 1.0000x reference)
//
#include <hip/hip_runtime.h>
#include <stdint.h>

#define NCLS 80
#define MAXB 150
#define BATCH 16
#define NANCH 25200
#define CAP 2048     // per-(image,class) candidate cap; mean fill ~600 -> >40 sigma
#define CAP2 12000   // hard bound: 80 classes * 150 kept max
#define NBINS 411    // score hi-bits (0x3F666666,0x3F800000] -> bins 0..410
#define SELCAP 2048
#define NREC_ALL 403200  // total records across levels/images
#define NF4_L0 408000u   // 16*1200*85/4
#define NF4_L01 2040000u // + 16*4800*85/4
#define NF4_ALL 8568000u // + 16*19200*85/4

typedef unsigned long long u64;
typedef unsigned int u32;
typedef float f4 __attribute__((ext_vector_type(4)));
typedef f4 f4u __attribute__((aligned(4)));  // 4B-aligned vector load

__device__ __forceinline__ float sigm(float x) { return 1.0f / (1.0f + expf(-x)); }

// ---------------- Pass 1a: headers -> boxes + cs (thread per record) ------------
__global__ __launch_bounds__(256) void header_kernel(
    const float* __restrict__ p0, const float* __restrict__ p1,
    const float* __restrict__ p2, float* __restrict__ boxes_ws,
    float* __restrict__ cs_arr) {
  int W = blockIdx.x * 256 + threadIdx.x;  // 0..403199, level-major record id
  int lvl, b, r;
  if (W < 19200) { lvl = 0; b = W / 1200; r = W - b * 1200; }
  else if (W < 96000) { int V = W - 19200; lvl = 1; b = V / 4800; r = V - b * 4800; }
  else { int V = W - 96000; lvl = 2; b = V / 19200; r = V - b * 19200; }
  const int gtab[3] = {20, 40, 80};
  const float rtab[3] = {32.f, 16.f, 8.f};
  const int nbt[3] = {0, 1200, 6000};
  const float awt[3][3] = {{116.f, 156.f, 373.f}, {30.f, 62.f, 59.f}, {10.f, 16.f, 33.f}};
  const float aht[3][3] = {{90.f, 198.f, 326.f}, {61.f, 45.f, 119.f}, {13.f, 30.f, 23.f}};
  const float* fm = (lvl == 0) ? p0 : ((lvl == 1) ? p1 : p2);
  int g = gtab[lvl];
  const float* p = fm + ((size_t)b * (g * g * 3) + r) * 85;
  f4 h = *(const f4u*)p;   // tx,ty,tw,th (4B-aligned vector load)
  float tc = p[4];
  int cell = r / 3, a = r - 3 * cell;
  int yy = cell / g, xx = cell - yy * g;
  float ratio = rtab[lvl];
  float cx = (sigm(h.x) + (float)xx) * ratio;
  float cy = (sigm(h.y) + (float)yy) * ratio;
  float w = expf(h.z) * awt[lvl][a];
  float hh = expf(h.w) * aht[lvl][a];
  int n = nbt[lvl] + r;
  reinterpret_cast<float4*>(boxes_ws)[(size_t)b * NANCH + n] = make_float4(
      cx - w * 0.5f, cy - hh * 0.5f, cx + w * 0.5f, cy + hh * 0.5f);
  cs_arr[W] = sigm(tc);  // score<=cs in fp32 -> cs>0.9 is a lossless gate
}

// ---------------- Pass 1b: streaming class scan (thread per float4) -------------
template <int NREC, int NBT, int CSB>
__device__ __forceinline__ void scan4(f4 v, u32 e, const float* __restrict__ cs_arr,
                                      u64* __restrict__ ck, int* __restrict__ cc) {
#pragma unroll
  for (int k = 0; k < 4; ++k) {
    float val = (k == 0) ? v.x : ((k == 1) ? v.y : ((k == 2) ? v.z : v.w));
    if (val > 2.19f) {  // sigm(2.19)=0.8993<0.9 -> lossless pre-cull (81% fail here)
      u32 ee = e + (u32)k;
      u32 R = ee / 85u, o = ee - R * 85u;  // record (level-local), offset in record
      if (o >= 5u) {
        float cs = cs_arr[CSB + R];
        if (cs > 0.9f) {
          float s = cs * sigm(val);
          if (s > 0.9f) {
            u32 b = R / (u32)NREC, r = R - b * (u32)NREC;
            u32 n = (u32)NBT + r;
            int bc = (int)b * NCLS + (int)(o - 5u);
            int pos = atomicAdd(&cc[bc], 1);
            if (pos < CAP)  // high = score bits, low = ~anchor (desc => idx-asc ties)
              ck[(size_t)bc * CAP + pos] =
                  ((u64)__float_as_uint(s) << 32) | (0xFFFFFFFFu - n);
          }
        }
      }
    }
  }
}

__global__ __launch_bounds__(256) void scan_kernel(
    const float* __restrict__ p0, const float* __restrict__ p1,
    const float* __restrict__ p2, const float* __restrict__ cs_arr,
    u64* __restrict__ cand_keys, int* __restrict__ cand_cnt) {
  u32 e4 = blockIdx.x * 256u + threadIdx.x;
  if (e4 >= NF4_ALL) return;
  if (e4 < NF4_L0) {
    f4 v = reinterpret_cast<const f4*>(p0)[e4];       // 16B-aligned stream
    scan4<1200, 0, 0>(v, e4 * 4u, cs_arr, cand_keys, cand_cnt);
  } else if (e4 < NF4_L01) {
    u32 t = e4 - NF4_L0;
    f4 v = reinterpret_cast<const f4*>(p1)[t];
    scan4<4800, 1200, 19200>(v, t * 4u, cs_arr, cand_keys, cand_cnt);
  } else {
    u32 t = e4 - NF4_L01;
    f4 v = reinterpret_cast<const f4*>(p2)[t];
    scan4<19200, 6000, 96000>(v, t * 4u, cs_arr, cand_keys, cand_cnt);
  }
}

// ---------------- Pass 2: rank-select top-150 + single-wave greedy NMS ----------
__global__ __launch_bounds__(256) void nms_kernel(
    const u64* __restrict__ cand_keys, const int* __restrict__ cand_cnt,
    const float* __restrict__ boxes_ws,
    u64* __restrict__ img_keys, int* __restrict__ img_cnt) {
  __shared__ u64 sk[CAP];       // 16 KB
  __shared__ u64 slot[MAXB];    // top-150 keys by exact rank
  __shared__ float4 sbox[MAXB];
  __shared__ float sarea[MAXB];
  int bc = blockIdx.x;
  int b = bc / NCLS, c = bc - b * NCLS;
  int tid = threadIdx.x;
  int count = cand_cnt[bc];
  if (count > CAP) count = CAP;
  const u64* src = cand_keys + (size_t)bc * CAP;
  for (int i = tid; i < count; i += 256) sk[i] = src[i];
  if (tid < MAXB) slot[tid] = 0;
  __syncthreads();
  // exact rank selection (keys unique); inner sk[j] is uniform -> LDS broadcast
  for (int i = tid; i < count; i += 256) {
    u64 k = sk[i];
    int rank = 0;
    for (int j = 0; j < count; ++j) rank += (sk[j] > k) ? 1 : 0;
    if (rank < MAXB) slot[rank] = k;
  }
  __syncthreads();
  if (tid < MAXB) {
    u64 k = slot[tid];
    float4 bx = make_float4(0.f, 0.f, 0.f, 0.f);
    if (k) {
      int n = (int)(0xFFFFFFFFu - (u32)(k & 0xFFFFFFFFu));
      bx = reinterpret_cast<const float4*>(boxes_ws)[(size_t)b * NANCH + n];
    }
    sbox[tid] = bx;
    sarea[tid] = (bx.z - bx.x) * (bx.w - bx.y);
  }
  __syncthreads();
  // single-wave greedy NMS: lane owns j in {lane, lane+64, lane+128}; no barriers.
  if (tid < 64) {
    u32 validm = 0, supm = 0;
    float4 myb[3];
    float mya[3];
    for (int s = 0; s < 3; ++s) {
      int j = tid + 64 * s;
      myb[s] = make_float4(0.f, 0.f, 0.f, 0.f);
      mya[s] = 0.f;
      if (j < MAXB && slot[j] != 0) {
        validm |= 1u << s;
        myb[s] = sbox[j];
        mya[s] = sarea[j];
      }
    }
    for (int i = 0; i < MAXB - 1; ++i) {
      int owner = i & 63, si = i >> 6;
      u32 f = __shfl(validm & ~supm, owner);  // keep_i broadcast from owner lane
      if ((f >> si) & 1) {
        float4 bi = sbox[i];
        float ai = sarea[i];
        for (int s = 0; s < 3; ++s) {
          int j = tid + 64 * s;
          if (j > i && j < MAXB && ((validm >> s) & 1) && !((supm >> s) & 1)) {
            float ltx = fmaxf(bi.x, myb[s].x);
            float lty = fmaxf(bi.y, myb[s].y);
            float rbx = fminf(bi.z, myb[s].z);
            float rby = fminf(bi.w, myb[s].w);
            float iw = fmaxf(rbx - ltx, 0.f);
            float ih = fmaxf(rby - lty, 0.f);
            float inter = iw * ih;
            float iou = inter / (ai + mya[s] - inter + 1e-9f);  // ref op order
            if (iou > 0.1f) supm |= 1u << s;
          }
        }
      }
    }
    // wave-aggregated append of kept entries to per-image list
    u32 keepm = validm & ~supm;
    u64 m0 = __ballot(keepm & 1u);
    u64 m1 = __ballot((keepm >> 1) & 1u);
    u64 m2 = __ballot((keepm >> 2) & 1u);
    int total = (int)(__popcll(m0) + __popcll(m1) + __popcll(m2));
    if (total > 0) {
      int base = 0;
      if (tid == 0) base = atomicAdd(&img_cnt[b], total);
      base = __shfl(base, 0);
      u64 lt = (1ull << tid) - 1;
      int off0 = (int)__popcll(m0 & lt);
      int off1 = (int)(__popcll(m0) + __popcll(m1 & lt));
      int off2 = (int)(__popcll(m0) + __popcll(m1) + __popcll(m2 & lt));
      for (int s = 0; s < 3; ++s) {
        if ((keepm >> s) & 1) {
          int j = tid + 64 * s;  // j == rank == top_k position
          u64 k = slot[j];
          u32 e = (u32)(c * MAXB + j);
          u32 anchor = (u32)(0xFFFFFFFFu - (u32)(k & 0xFFFFFFFFu));
          int pos = base + ((s == 0) ? off0 : ((s == 1) ? off1 : off2));
          // key = [score:32][(0x3FFF - e):14][anchor:15]  (unique per entry)
          img_keys[(size_t)b * CAP2 + pos] =
              ((k >> 32) << 32) | ((u64)(0x3FFFu - e) << 15) | anchor;
        }
      }
    }
  }
}

// ---------------- Pass 3: per-image top-150 via exact histogram select ----------
__global__ __launch_bounds__(1024) void final_kernel(
    const u64* __restrict__ img_keys, const int* __restrict__ img_cnt,
    const float* __restrict__ boxes_ws, float* __restrict__ out) {
  __shared__ u32 hist[NBINS];
  __shared__ u64 sel[SELCAP];   // 16 KB
  __shared__ u64 slot[MAXB];
  __shared__ int sT, sCge, nsel;
  int b = blockIdx.x, tid = threadIdx.x;
  int L = img_cnt[b];
  if (L > CAP2) L = CAP2;
  const u64* src = img_keys + (size_t)b * CAP2;
  for (int i = tid; i < NBINS; i += 1024) hist[i] = 0;
  if (tid < MAXB) slot[tid] = 0;
  if (tid == 0) nsel = 0;
  __syncthreads();
  for (int i = tid; i < L; i += 1024) {
    u32 hi = (u32)(src[i] >> 32);
    atomicAdd(&hist[(hi - 0x3F666000u) >> 12], 1u);
  }
  __syncthreads();
  if (tid == 0) {
    int target = (L < MAXB) ? L : MAXB;
    int acc = 0, T = 0;
    if (target > 0) {
      for (int j = NBINS - 1; j >= 0; --j) {
        acc += (int)hist[j];
        if (acc >= target) { T = j; break; }
      }
    }
    sT = T;
    sCge = acc;
  }
  __syncthreads();
  int T = sT, cge = sCge;
  float* ob = out;                      // [B][150][4]
  float* osc = out + BATCH * MAXB * 4;  // [B][150]
  float* olb = out + BATCH * MAXB * 5;  // [B][150] labels (as float)
  if (cge <= SELCAP) {
    // fast path: compact bins >= T, exact rank-select the small set
    for (int i = tid; i < L; i += 1024) {
      u64 k = src[i];
      if ((int)(((u32)(k >> 32) - 0x3F666000u) >> 12) >= T) {
        int pos = atomicAdd(&nsel, 1);
        sel[pos] = k;
      }
    }
    __syncthreads();
    int C = nsel;
    for (int i = tid; i < C; i += 1024) {
      u64 k = sel[i];
      int rank = 0;
      for (int j = 0; j < C; ++j) rank += (sel[j] > k) ? 1 : 0;  // LDS broadcast
      if (rank < MAXB) slot[rank] = k;
    }
    __syncthreads();
  } else {
    // fallback (pathological concentration): exact rank-select over global list
    for (int i = tid; i < L; i += 1024) {
      u64 k = src[i];
      int rank = 0;
      for (int j = 0; j < L; ++j) rank += (src[j] > k) ? 1 : 0;
      if (rank < MAXB) slot[rank] = k;
    }
    __syncthreads();
  }
  if (tid < MAXB) {
    u64 k = slot[tid];
    float* q = ob + ((size_t)b * MAXB + tid) * 4;
    if (k) {
      u32 e = 0x3FFFu - (u32)((k >> 15) & 0x3FFFu);
      int c = (int)(e / MAXB);
      int anchor = (int)(k & 0x7FFFu);
      float4 bx = reinterpret_cast<const float4*>(boxes_ws)[(size_t)b * NANCH + anchor];
      q[0] = bx.x; q[1] = bx.y; q[2] = bx.z; q[3] = bx.w;
      osc[(size_t)b * MAXB + tid] = __uint_as_float((u32)(k >> 32));
      olb[(size_t)b * MAXB + tid] = (float)c;
    } else {
      q[0] = q[1] = q[2] = q[3] = -1.f;
      osc[(size_t)b * MAXB + tid] = -1.f;
      olb[(size_t)b * MAXB + tid] = -1.f;
    }
  }
}

extern "C" void kernel_launch(void* const* d_in, const int* in_sizes, int n_in,
                              void* d_out, int out_size, void* d_ws, size_t ws_size,
                              hipStream_t stream) {
  (void)in_sizes; (void)n_in; (void)out_size; (void)ws_size;
  const float* p0 = (const float*)d_in[0];  // [16,20,20,255] anchors[6:9]
  const float* p1 = (const float*)d_in[1];  // [16,40,40,255] anchors[3:6]
  const float* p2 = (const float*)d_in[2];  // [16,80,80,255] anchors[0:3]
  char* ws = (char*)d_ws;
  float* boxes_ws = (float*)ws;              // 16*25200*16 B          -> 6,451,200
  int* cand_cnt = (int*)(ws + 6451200);      // 1280 i32               -> 6,456,320
  int* img_cnt = (int*)(ws + 6456320);       // 16 i32 (+pad)          -> 6,456,384
  float* cs_arr = (float*)(ws + 6456384);    // 403200 f32             -> 8,069,184
  u64* cand_keys = (u64*)(ws + 8069184);     // 1280*2048 u64          -> 29,040,704
  u64* img_keys = (u64*)(ws + 29040704);     // 16*12000 u64           -> 30,576,704

  hipMemsetAsync(cand_cnt, 0, (NCLS * BATCH + BATCH) * sizeof(int), stream);

  header_kernel<<<NREC_ALL / 256, 256, 0, stream>>>(p0, p1, p2, boxes_ws, cs_arr);
  scan_kernel<<<(NF4_ALL + 255) / 256, 256, 0, stream>>>(p0, p1, p2, cs_arr,
                                                         cand_keys, cand_cnt);
  nms_kernel<<<BATCH * NCLS, 256, 0, stream>>>(cand_keys, cand_cnt, boxes_ws,
                                               img_keys, img_cnt);
  final_kernel<<<BATCH, 1024, 0, stream>>>(img_keys, img_cnt, boxes_ws, (float*)d_out);
}

// Round 7
// 234.747 us; speedup vs baseline: 2.5332x; 2.5332x over previous
//
#include <hip/hip_runtime.h>
#include <stdint.h>

#define NCLS 80
#define MAXB 150
#define BATCH 16
#define NANCH 25200
#define CAP 2048     // per-(image,class) candidate cap; mean fill ~600 -> >40 sigma
#define CAP2 12000   // hard bound: 80 classes * 150 kept max
#define NBINS 411    // score hi-bits (0x3F666666,0x3F800000] -> bins 0..410
#define SELCAP 2048
#define NREC_ALL 403200  // total records across levels/images
#define NF4_L0 408000u   // 16*1200*85/4
#define NF4_L01 2040000u // + 16*4800*85/4
#define NF4_ALL 8568000u // + 16*19200*85/4
#define CPAD 16          // counters padded to one per 64B line (atomic contention fix)

typedef unsigned long long u64;
typedef unsigned int u32;
typedef float f4 __attribute__((ext_vector_type(4)));
typedef f4 f4u __attribute__((aligned(4)));  // 4B-aligned vector load

__device__ __forceinline__ float sigm(float x) { return 1.0f / (1.0f + expf(-x)); }

// ---------------- Pass 1a: headers -> boxes + cs (thread per record) ------------
__global__ __launch_bounds__(256) void header_kernel(
    const float* __restrict__ p0, const float* __restrict__ p1,
    const float* __restrict__ p2, float* __restrict__ boxes_ws,
    float* __restrict__ cs_arr) {
  int W = blockIdx.x * 256 + threadIdx.x;  // 0..403199, level-major record id
  int lvl, b, r;
  if (W < 19200) { lvl = 0; b = W / 1200; r = W - b * 1200; }
  else if (W < 96000) { int V = W - 19200; lvl = 1; b = V / 4800; r = V - b * 4800; }
  else { int V = W - 96000; lvl = 2; b = V / 19200; r = V - b * 19200; }
  const int gtab[3] = {20, 40, 80};
  const float rtab[3] = {32.f, 16.f, 8.f};
  const int nbt[3] = {0, 1200, 6000};
  const float awt[3][3] = {{116.f, 156.f, 373.f}, {30.f, 62.f, 59.f}, {10.f, 16.f, 33.f}};
  const float aht[3][3] = {{90.f, 198.f, 326.f}, {61.f, 45.f, 119.f}, {13.f, 30.f, 23.f}};
  const float* fm = (lvl == 0) ? p0 : ((lvl == 1) ? p1 : p2);
  int g = gtab[lvl];
  const float* p = fm + ((size_t)b * (g * g * 3) + r) * 85;
  f4 h = *(const f4u*)p;   // tx,ty,tw,th (4B-aligned vector load)
  float tc = p[4];
  int cell = r / 3, a = r - 3 * cell;
  int yy = cell / g, xx = cell - yy * g;
  float ratio = rtab[lvl];
  float cx = (sigm(h.x) + (float)xx) * ratio;
  float cy = (sigm(h.y) + (float)yy) * ratio;
  float w = expf(h.z) * awt[lvl][a];
  float hh = expf(h.w) * aht[lvl][a];
  int n = nbt[lvl] + r;
  reinterpret_cast<float4*>(boxes_ws)[(size_t)b * NANCH + n] = make_float4(
      cx - w * 0.5f, cy - hh * 0.5f, cx + w * 0.5f, cy + hh * 0.5f);
  cs_arr[W] = sigm(tc);  // score<=cs in fp32 -> cs>0.9 is a lossless gate
}

// ---------------- Pass 1b: streaming class scan (thread per float4) -------------
template <int NREC, int NBT, int CSB>
__device__ __forceinline__ void scan4(f4 v, u32 e, const float* __restrict__ cs_arr,
                                      u64* __restrict__ ck, int* __restrict__ cc) {
#pragma unroll
  for (int k = 0; k < 4; ++k) {
    float val = (k == 0) ? v.x : ((k == 1) ? v.y : ((k == 2) ? v.z : v.w));
    if (val > 2.19f) {  // sigm(2.19)=0.8993<0.9 -> lossless pre-cull (81% fail here)
      u32 ee = e + (u32)k;
      u32 R = ee / 85u, o = ee - R * 85u;  // record (level-local), offset in record
      if (o >= 5u) {
        float cs = cs_arr[CSB + R];
        if (cs > 0.9f) {
          float s = cs * sigm(val);
          if (s > 0.9f) {
            u32 b = R / (u32)NREC, r = R - b * (u32)NREC;
            u32 n = (u32)NBT + r;
            int bc = (int)b * NCLS + (int)(o - 5u);
            int pos = atomicAdd(&cc[bc * CPAD], 1);  // padded: 1 counter / 64B line
            if (pos < CAP)  // high = score bits, low = ~anchor (desc => idx-asc ties)
              ck[(size_t)bc * CAP + pos] =
                  ((u64)__float_as_uint(s) << 32) | (0xFFFFFFFFu - n);
          }
        }
      }
    }
  }
}

__global__ __launch_bounds__(256) void scan_kernel(
    const float* __restrict__ p0, const float* __restrict__ p1,
    const float* __restrict__ p2, const float* __restrict__ cs_arr,
    u64* __restrict__ cand_keys, int* __restrict__ cand_cnt) {
  u32 e4 = blockIdx.x * 256u + threadIdx.x;
  if (e4 >= NF4_ALL) return;
  if (e4 < NF4_L0) {
    f4 v = reinterpret_cast<const f4*>(p0)[e4];       // 16B-aligned stream
    scan4<1200, 0, 0>(v, e4 * 4u, cs_arr, cand_keys, cand_cnt);
  } else if (e4 < NF4_L01) {
    u32 t = e4 - NF4_L0;
    f4 v = reinterpret_cast<const f4*>(p1)[t];
    scan4<4800, 1200, 19200>(v, t * 4u, cs_arr, cand_keys, cand_cnt);
  } else {
    u32 t = e4 - NF4_L01;
    f4 v = reinterpret_cast<const f4*>(p2)[t];
    scan4<19200, 6000, 96000>(v, t * 4u, cs_arr, cand_keys, cand_cnt);
  }
}

// ---------------- Pass 2: rank-select top-150 + single-wave greedy NMS ----------
__global__ __launch_bounds__(256) void nms_kernel(
    const u64* __restrict__ cand_keys, const int* __restrict__ cand_cnt,
    const float* __restrict__ boxes_ws,
    u64* __restrict__ img_keys, int* __restrict__ img_cnt) {
  __shared__ u64 sk[CAP];       // 16 KB
  __shared__ u64 slot[MAXB];    // top-150 keys by exact rank
  __shared__ float4 sbox[MAXB];
  __shared__ float sarea[MAXB];
  int bc = blockIdx.x;
  int b = bc / NCLS, c = bc - b * NCLS;
  int tid = threadIdx.x;
  int count = cand_cnt[bc * CPAD];
  if (count > CAP) count = CAP;
  const u64* src = cand_keys + (size_t)bc * CAP;
  for (int i = tid; i < count; i += 256) sk[i] = src[i];
  if (tid < MAXB) slot[tid] = 0;
  __syncthreads();
  // exact rank selection (keys unique); inner sk[j] is uniform -> LDS broadcast
  for (int i = tid; i < count; i += 256) {
    u64 k = sk[i];
    int rank = 0;
    for (int j = 0; j < count; ++j) rank += (sk[j] > k) ? 1 : 0;
    if (rank < MAXB) slot[rank] = k;
  }
  __syncthreads();
  if (tid < MAXB) {
    u64 k = slot[tid];
    float4 bx = make_float4(0.f, 0.f, 0.f, 0.f);
    if (k) {
      int n = (int)(0xFFFFFFFFu - (u32)(k & 0xFFFFFFFFu));
      bx = reinterpret_cast<const float4*>(boxes_ws)[(size_t)b * NANCH + n];
    }
    sbox[tid] = bx;
    sarea[tid] = (bx.z - bx.x) * (bx.w - bx.y);
  }
  __syncthreads();
  // single-wave greedy NMS: lane owns j in {lane, lane+64, lane+128}; no barriers.
  if (tid < 64) {
    u32 validm = 0, supm = 0;
    float4 myb[3];
    float mya[3];
    for (int s = 0; s < 3; ++s) {
      int j = tid + 64 * s;
      myb[s] = make_float4(0.f, 0.f, 0.f, 0.f);
      mya[s] = 0.f;
      if (j < MAXB && slot[j] != 0) {
        validm |= 1u << s;
        myb[s] = sbox[j];
        mya[s] = sarea[j];
      }
    }
    for (int i = 0; i < MAXB - 1; ++i) {
      int owner = i & 63, si = i >> 6;
      u32 f = __shfl(validm & ~supm, owner);  // keep_i broadcast from owner lane
      if ((f >> si) & 1) {
        float4 bi = sbox[i];
        float ai = sarea[i];
        for (int s = 0; s < 3; ++s) {
          int j = tid + 64 * s;
          if (j > i && j < MAXB && ((validm >> s) & 1) && !((supm >> s) & 1)) {
            float ltx = fmaxf(bi.x, myb[s].x);
            float lty = fmaxf(bi.y, myb[s].y);
            float rbx = fminf(bi.z, myb[s].z);
            float rby = fminf(bi.w, myb[s].w);
            float iw = fmaxf(rbx - ltx, 0.f);
            float ih = fmaxf(rby - lty, 0.f);
            float inter = iw * ih;
            float iou = inter / (ai + mya[s] - inter + 1e-9f);  // ref op order
            if (iou > 0.1f) supm |= 1u << s;
          }
        }
      }
    }
    // wave-aggregated append of kept entries to per-image list
    u32 keepm = validm & ~supm;
    u64 m0 = __ballot(keepm & 1u);
    u64 m1 = __ballot((keepm >> 1) & 1u);
    u64 m2 = __ballot((keepm >> 2) & 1u);
    int total = (int)(__popcll(m0) + __popcll(m1) + __popcll(m2));
    if (total > 0) {
      int base = 0;
      if (tid == 0) base = atomicAdd(&img_cnt[b * CPAD], total);
      base = __shfl(base, 0);
      u64 lt = (1ull << tid) - 1;
      int off0 = (int)__popcll(m0 & lt);
      int off1 = (int)(__popcll(m0) + __popcll(m1 & lt));
      int off2 = (int)(__popcll(m0) + __popcll(m1) + __popcll(m2 & lt));
      for (int s = 0; s < 3; ++s) {
        if ((keepm >> s) & 1) {
          int j = tid + 64 * s;  // j == rank == top_k position
          u64 k = slot[j];
          u32 e = (u32)(c * MAXB + j);
          u32 anchor = (u32)(0xFFFFFFFFu - (u32)(k & 0xFFFFFFFFu));
          int pos = base + ((s == 0) ? off0 : ((s == 1) ? off1 : off2));
          // key = [score:32][(0x3FFF - e):14][anchor:15]  (unique per entry)
          img_keys[(size_t)b * CAP2 + pos] =
              ((k >> 32) << 32) | ((u64)(0x3FFFu - e) << 15) | anchor;
        }
      }
    }
  }
}

// ---------------- Pass 3: per-image top-150 via exact histogram select ----------
__global__ __launch_bounds__(1024) void final_kernel(
    const u64* __restrict__ img_keys, const int* __restrict__ img_cnt,
    const float* __restrict__ boxes_ws, float* __restrict__ out) {
  __shared__ u32 hist[NBINS];
  __shared__ u64 sel[SELCAP];   // 16 KB
  __shared__ u64 slot[MAXB];
  __shared__ int sT, sCge, nsel;
  int b = blockIdx.x, tid = threadIdx.x;
  int L = img_cnt[b * CPAD];
  if (L > CAP2) L = CAP2;
  const u64* src = img_keys + (size_t)b * CAP2;
  for (int i = tid; i < NBINS; i += 1024) hist[i] = 0;
  if (tid < MAXB) slot[tid] = 0;
  if (tid == 0) nsel = 0;
  __syncthreads();
  for (int i = tid; i < L; i += 1024) {
    u32 hi = (u32)(src[i] >> 32);
    atomicAdd(&hist[(hi - 0x3F666000u) >> 12], 1u);
  }
  __syncthreads();
  if (tid == 0) {
    int target = (L < MAXB) ? L : MAXB;
    int acc = 0, T = 0;
    if (target > 0) {
      for (int j = NBINS - 1; j >= 0; --j) {
        acc += (int)hist[j];
        if (acc >= target) { T = j; break; }
      }
    }
    sT = T;
    sCge = acc;
  }
  __syncthreads();
  int T = sT, cge = sCge;
  float* ob = out;                      // [B][150][4]
  float* osc = out + BATCH * MAXB * 4;  // [B][150]
  float* olb = out + BATCH * MAXB * 5;  // [B][150] labels (as float)
  if (cge <= SELCAP) {
    // fast path: compact bins >= T, exact rank-select the small set
    for (int i = tid; i < L; i += 1024) {
      u64 k = src[i];
      if ((int)(((u32)(k >> 32) - 0x3F666000u) >> 12) >= T) {
        int pos = atomicAdd(&nsel, 1);
        sel[pos] = k;
      }
    }
    __syncthreads();
    int C = nsel;
    for (int i = tid; i < C; i += 1024) {
      u64 k = sel[i];
      int rank = 0;
      for (int j = 0; j < C; ++j) rank += (sel[j] > k) ? 1 : 0;  // LDS broadcast
      if (rank < MAXB) slot[rank] = k;
    }
    __syncthreads();
  } else {
    // fallback (pathological concentration): exact rank-select over global list
    for (int i = tid; i < L; i += 1024) {
      u64 k = src[i];
      int rank = 0;
      for (int j = 0; j < L; ++j) rank += (src[j] > k) ? 1 : 0;
      if (rank < MAXB) slot[rank] = k;
    }
    __syncthreads();
  }
  if (tid < MAXB) {
    u64 k = slot[tid];
    float* q = ob + ((size_t)b * MAXB + tid) * 4;
    if (k) {
      u32 e = 0x3FFFu - (u32)((k >> 15) & 0x3FFFu);
      int c = (int)(e / MAXB);
      int anchor = (int)(k & 0x7FFFu);
      float4 bx = reinterpret_cast<const float4*>(boxes_ws)[(size_t)b * NANCH + anchor];
      q[0] = bx.x; q[1] = bx.y; q[2] = bx.z; q[3] = bx.w;
      osc[(size_t)b * MAXB + tid] = __uint_as_float((u32)(k >> 32));
      olb[(size_t)b * MAXB + tid] = (float)c;
    } else {
      q[0] = q[1] = q[2] = q[3] = -1.f;
      osc[(size_t)b * MAXB + tid] = -1.f;
      olb[(size_t)b * MAXB + tid] = -1.f;
    }
  }
}

extern "C" void kernel_launch(void* const* d_in, const int* in_sizes, int n_in,
                              void* d_out, int out_size, void* d_ws, size_t ws_size,
                              hipStream_t stream) {
  (void)in_sizes; (void)n_in; (void)out_size; (void)ws_size;
  const float* p0 = (const float*)d_in[0];  // [16,20,20,255] anchors[6:9]
  const float* p1 = (const float*)d_in[1];  // [16,40,40,255] anchors[3:6]
  const float* p2 = (const float*)d_in[2];  // [16,80,80,255] anchors[0:3]
  char* ws = (char*)d_ws;
  float* boxes_ws = (float*)ws;              // 16*25200*16 B          -> 6,451,200
  int* cand_cnt = (int*)(ws + 6451200);      // 1280*16 i32 (padded)   -> 6,533,120
  int* img_cnt = (int*)(ws + 6533120);       // 16*16 i32 (padded)     -> 6,534,144
  float* cs_arr = (float*)(ws + 6534144);    // 403200 f32             -> 8,146,944
  u64* cand_keys = (u64*)(ws + 8146944);     // 1280*2048 u64          -> 29,118,464
  u64* img_keys = (u64*)(ws + 29118464);     // 16*12000 u64           -> 30,654,464

  hipMemsetAsync(cand_cnt, 0, (NCLS * BATCH + BATCH) * CPAD * sizeof(int), stream);

  header_kernel<<<NREC_ALL / 256, 256, 0, stream>>>(p0, p1, p2, boxes_ws, cs_arr);
  scan_kernel<<<(NF4_ALL + 255) / 256, 256, 0, stream>>>(p0, p1, p2, cs_arr,
                                                         cand_keys, cand_cnt);
  nms_kernel<<<BATCH * NCLS, 256, 0, stream>>>(cand_keys, cand_cnt, boxes_ws,
                                               img_keys, img_cnt);
  final_kernel<<<BATCH, 1024, 0, stream>>>(img_keys, img_cnt, boxes_ws, (float*)d_out);
}

// Round 8
// 173.255 us; speedup vs baseline: 3.4323x; 1.3549x over previous
//
#include <hip/hip_runtime.h>
#include <stdint.h>

#define NCLS 80
#define MAXB 150
#define BATCH 16
#define NANCH 25200
#define CAP 2048     // per-(image,class) candidate cap; mean fill ~600 -> >40 sigma
#define CAP2 12000   // hard bound: 80 classes * 150 kept max
#define NBINS 411    // score hi-bits (0x3F666666,0x3F800000] -> bins 0..410
#define SELCAP 2048
#define NSEL 1024    // nms histogram-compact capacity (expected ~155)
#define NREC_ALL 403200  // total records across levels/images
#define NF4_L0 408000u   // 16*1200*85/4
#define NF4_L01 2040000u // + 16*4800*85/4
#define NF4_ALL 8568000u // + 16*19200*85/4
#define CPAD 16          // counters padded to one per 64B line (atomic contention fix)
#define SCAN_PER 4       // float4s per thread in scan (MLP)

typedef unsigned long long u64;
typedef unsigned int u32;
typedef float f4 __attribute__((ext_vector_type(4)));
typedef f4 f4u __attribute__((aligned(4)));  // 4B-aligned vector load

__device__ __forceinline__ float sigm(float x) { return 1.0f / (1.0f + expf(-x)); }

// ---------------- Pass 1a: headers -> boxes + cs (thread per record) ------------
__global__ __launch_bounds__(256) void header_kernel(
    const float* __restrict__ p0, const float* __restrict__ p1,
    const float* __restrict__ p2, float* __restrict__ boxes_ws,
    float* __restrict__ cs_arr) {
  int W = blockIdx.x * 256 + threadIdx.x;  // 0..403199, level-major record id
  int lvl, b, r;
  if (W < 19200) { lvl = 0; b = W / 1200; r = W - b * 1200; }
  else if (W < 96000) { int V = W - 19200; lvl = 1; b = V / 4800; r = V - b * 4800; }
  else { int V = W - 96000; lvl = 2; b = V / 19200; r = V - b * 19200; }
  const int gtab[3] = {20, 40, 80};
  const float rtab[3] = {32.f, 16.f, 8.f};
  const int nbt[3] = {0, 1200, 6000};
  const float awt[3][3] = {{116.f, 156.f, 373.f}, {30.f, 62.f, 59.f}, {10.f, 16.f, 33.f}};
  const float aht[3][3] = {{90.f, 198.f, 326.f}, {61.f, 45.f, 119.f}, {13.f, 30.f, 23.f}};
  const float* fm = (lvl == 0) ? p0 : ((lvl == 1) ? p1 : p2);
  int g = gtab[lvl];
  const float* p = fm + ((size_t)b * (g * g * 3) + r) * 85;
  f4 h = *(const f4u*)p;   // tx,ty,tw,th (4B-aligned vector load)
  float tc = p[4];
  int cell = r / 3, a = r - 3 * cell;
  int yy = cell / g, xx = cell - yy * g;
  float ratio = rtab[lvl];
  float cx = (sigm(h.x) + (float)xx) * ratio;
  float cy = (sigm(h.y) + (float)yy) * ratio;
  float w = expf(h.z) * awt[lvl][a];
  float hh = expf(h.w) * aht[lvl][a];
  int n = nbt[lvl] + r;
  reinterpret_cast<float4*>(boxes_ws)[(size_t)b * NANCH + n] = make_float4(
      cx - w * 0.5f, cy - hh * 0.5f, cx + w * 0.5f, cy + hh * 0.5f);
  cs_arr[W] = sigm(tc);  // score<=cs in fp32 -> cs>0.9 is a lossless gate
}

// ---------------- Pass 1b: streaming class scan (SCAN_PER float4s / thread) -----
template <int NREC, int NBT, int CSB>
__device__ __forceinline__ void scan4(f4 v, u32 e, const float* __restrict__ cs_arr,
                                      u64* __restrict__ ck, int* __restrict__ cc) {
#pragma unroll
  for (int k = 0; k < 4; ++k) {
    float val = (k == 0) ? v.x : ((k == 1) ? v.y : ((k == 2) ? v.z : v.w));
    if (val > 2.19f) {  // sigm(2.19)=0.8993<0.9 -> lossless pre-cull (81% fail here)
      u32 ee = e + (u32)k;
      u32 R = ee / 85u, o = ee - R * 85u;  // record (level-local), offset in record
      if (o >= 5u) {
        float cs = cs_arr[CSB + R];
        if (cs > 0.9f) {
          float s = cs * sigm(val);
          if (s > 0.9f) {
            u32 b = R / (u32)NREC, r = R - b * (u32)NREC;
            u32 n = (u32)NBT + r;
            int bc = (int)b * NCLS + (int)(o - 5u);
            int pos = atomicAdd(&cc[bc * CPAD], 1);  // padded: 1 counter / 64B line
            if (pos < CAP)  // high = score bits, low = ~anchor (desc => idx-asc ties)
              ck[(size_t)bc * CAP + pos] =
                  ((u64)__float_as_uint(s) << 32) | (0xFFFFFFFFu - n);
          }
        }
      }
    }
  }
}

__global__ __launch_bounds__(256) void scan_kernel(
    const float* __restrict__ p0, const float* __restrict__ p1,
    const float* __restrict__ p2, const float* __restrict__ cs_arr,
    u64* __restrict__ cand_keys, int* __restrict__ cand_cnt) {
  u32 base = blockIdx.x * (256u * SCAN_PER) + threadIdx.x;
  f4 v[SCAN_PER];
  u32 t[SCAN_PER];
  int lv[SCAN_PER];
#pragma unroll
  for (int j = 0; j < SCAN_PER; ++j) {  // issue all loads first (4 in flight)
    u32 e4 = base + 256u * j;
    lv[j] = -1;
    if (e4 < NF4_L0) {
      lv[j] = 0; t[j] = e4;
      v[j] = reinterpret_cast<const f4*>(p0)[e4];
    } else if (e4 < NF4_L01) {
      lv[j] = 1; t[j] = e4 - NF4_L0;
      v[j] = reinterpret_cast<const f4*>(p1)[t[j]];
    } else if (e4 < NF4_ALL) {
      lv[j] = 2; t[j] = e4 - NF4_L01;
      v[j] = reinterpret_cast<const f4*>(p2)[t[j]];
    }
  }
#pragma unroll
  for (int j = 0; j < SCAN_PER; ++j) {
    if (lv[j] == 0) scan4<1200, 0, 0>(v[j], t[j] * 4u, cs_arr, cand_keys, cand_cnt);
    else if (lv[j] == 1) scan4<4800, 1200, 19200>(v[j], t[j] * 4u, cs_arr, cand_keys, cand_cnt);
    else if (lv[j] == 2) scan4<19200, 6000, 96000>(v[j], t[j] * 4u, cs_arr, cand_keys, cand_cnt);
  }
}

// ------- Pass 2: histogram-select top-150 + rank + single-wave greedy NMS -------
__global__ __launch_bounds__(256) void nms_kernel(
    const u64* __restrict__ cand_keys, const int* __restrict__ cand_cnt,
    const float* __restrict__ boxes_ws,
    u64* __restrict__ img_keys, int* __restrict__ img_cnt) {
  __shared__ u32 hist[NBINS];
  __shared__ u64 sel[NSEL];     // 8 KB
  __shared__ u64 slot[MAXB];    // top-150 keys by exact rank
  __shared__ float4 sbox[MAXB];
  __shared__ float sarea[MAXB];
  __shared__ int sT, sCge, nsel;
  int bc = blockIdx.x;
  int b = bc / NCLS, c = bc - b * NCLS;
  int tid = threadIdx.x;
  int count = cand_cnt[bc * CPAD];
  if (count > CAP) count = CAP;
  const u64* src = cand_keys + (size_t)bc * CAP;
  for (int i = tid; i < NBINS; i += 256) hist[i] = 0;
  if (tid < MAXB) slot[tid] = 0;
  if (tid == 0) nsel = 0;
  __syncthreads();
  for (int i = tid; i < count; i += 256)
    atomicAdd(&hist[((u32)(src[i] >> 32) - 0x3F666000u) >> 12], 1u);
  __syncthreads();
  if (tid == 0) {
    int target = (count < MAXB) ? count : MAXB;
    int acc = 0, T = 0;
    if (target > 0) {
      for (int j = NBINS - 1; j >= 0; --j) {
        acc += (int)hist[j];
        if (acc >= target) { T = j; break; }
      }
    }
    sT = T;
    sCge = acc;
  }
  __syncthreads();
  int T = sT;
  if (sCge <= NSEL) {
    // compact bins >= T (superset of exact top-target; bin order is key order)
    for (int i = tid; i < count; i += 256) {
      u64 k = src[i];
      if ((int)(((u32)(k >> 32) - 0x3F666000u) >> 12) >= T) {
        int pos = atomicAdd(&nsel, 1);
        sel[pos] = k;
      }
    }
    __syncthreads();
    int C = nsel;
    for (int i = tid; i < C; i += 256) {
      u64 k = sel[i];
      int rank = 0;
      for (int j = 0; j < C; ++j) rank += (sel[j] > k) ? 1 : 0;  // LDS broadcast
      if (rank < MAXB) slot[rank] = k;
    }
  } else {
    // fallback (pathological bin concentration): full exact rank-select
    for (int i = tid; i < count; i += 256) {
      u64 k = src[i];
      int rank = 0;
      for (int j = 0; j < count; ++j) rank += (src[j] > k) ? 1 : 0;
      if (rank < MAXB) slot[rank] = k;
    }
  }
  __syncthreads();
  if (tid < MAXB) {
    u64 k = slot[tid];
    float4 bx = make_float4(0.f, 0.f, 0.f, 0.f);
    if (k) {
      int n = (int)(0xFFFFFFFFu - (u32)(k & 0xFFFFFFFFu));
      bx = reinterpret_cast<const float4*>(boxes_ws)[(size_t)b * NANCH + n];
    }
    sbox[tid] = bx;
    sarea[tid] = (bx.z - bx.x) * (bx.w - bx.y);
  }
  __syncthreads();
  // single-wave greedy NMS: lane owns j in {lane, lane+64, lane+128}; no barriers.
  if (tid < 64) {
    u32 validm = 0, supm = 0;
    float4 myb[3];
    float mya[3];
    for (int s = 0; s < 3; ++s) {
      int j = tid + 64 * s;
      myb[s] = make_float4(0.f, 0.f, 0.f, 0.f);
      mya[s] = 0.f;
      if (j < MAXB && slot[j] != 0) {
        validm |= 1u << s;
        myb[s] = sbox[j];
        mya[s] = sarea[j];
      }
    }
    for (int i = 0; i < MAXB - 1; ++i) {
      int owner = i & 63, si = i >> 6;
      u32 f = __shfl(validm & ~supm, owner);  // keep_i broadcast from owner lane
      if ((f >> si) & 1) {
        float4 bi = sbox[i];
        float ai = sarea[i];
        for (int s = 0; s < 3; ++s) {
          int j = tid + 64 * s;
          if (j > i && j < MAXB && ((validm >> s) & 1) && !((supm >> s) & 1)) {
            float ltx = fmaxf(bi.x, myb[s].x);
            float lty = fmaxf(bi.y, myb[s].y);
            float rbx = fminf(bi.z, myb[s].z);
            float rby = fminf(bi.w, myb[s].w);
            float iw = fmaxf(rbx - ltx, 0.f);
            float ih = fmaxf(rby - lty, 0.f);
            float inter = iw * ih;
            float iou = inter / (ai + mya[s] - inter + 1e-9f);  // ref op order
            if (iou > 0.1f) supm |= 1u << s;
          }
        }
      }
    }
    // wave-aggregated append of kept entries to per-image list
    u32 keepm = validm & ~supm;
    u64 m0 = __ballot(keepm & 1u);
    u64 m1 = __ballot((keepm >> 1) & 1u);
    u64 m2 = __ballot((keepm >> 2) & 1u);
    int total = (int)(__popcll(m0) + __popcll(m1) + __popcll(m2));
    if (total > 0) {
      int base = 0;
      if (tid == 0) base = atomicAdd(&img_cnt[b * CPAD], total);
      base = __shfl(base, 0);
      u64 lt = (1ull << tid) - 1;
      int off0 = (int)__popcll(m0 & lt);
      int off1 = (int)(__popcll(m0) + __popcll(m1 & lt));
      int off2 = (int)(__popcll(m0) + __popcll(m1) + __popcll(m2 & lt));
      for (int s = 0; s < 3; ++s) {
        if ((keepm >> s) & 1) {
          int j = tid + 64 * s;  // j == rank == top_k position
          u64 k = slot[j];
          u32 e = (u32)(c * MAXB + j);
          u32 anchor = (u32)(0xFFFFFFFFu - (u32)(k & 0xFFFFFFFFu));
          int pos = base + ((s == 0) ? off0 : ((s == 1) ? off1 : off2));
          // key = [score:32][(0x3FFF - e):14][anchor:15]  (unique per entry)
          img_keys[(size_t)b * CAP2 + pos] =
              ((k >> 32) << 32) | ((u64)(0x3FFFu - e) << 15) | anchor;
        }
      }
    }
  }
}

// ---------------- Pass 3: per-image top-150 via exact histogram select ----------
__global__ __launch_bounds__(1024) void final_kernel(
    const u64* __restrict__ img_keys, const int* __restrict__ img_cnt,
    const float* __restrict__ boxes_ws, float* __restrict__ out) {
  __shared__ u32 hist[NBINS];
  __shared__ u64 sel[SELCAP];   // 16 KB
  __shared__ u64 slot[MAXB];
  __shared__ int sT, sCge, nsel;
  int b = blockIdx.x, tid = threadIdx.x;
  int L = img_cnt[b * CPAD];
  if (L > CAP2) L = CAP2;
  const u64* src = img_keys + (size_t)b * CAP2;
  for (int i = tid; i < NBINS; i += 1024) hist[i] = 0;
  if (tid < MAXB) slot[tid] = 0;
  if (tid == 0) nsel = 0;
  __syncthreads();
  for (int i = tid; i < L; i += 1024) {
    u32 hi = (u32)(src[i] >> 32);
    atomicAdd(&hist[(hi - 0x3F666000u) >> 12], 1u);
  }
  __syncthreads();
  if (tid == 0) {
    int target = (L < MAXB) ? L : MAXB;
    int acc = 0, T = 0;
    if (target > 0) {
      for (int j = NBINS - 1; j >= 0; --j) {
        acc += (int)hist[j];
        if (acc >= target) { T = j; break; }
      }
    }
    sT = T;
    sCge = acc;
  }
  __syncthreads();
  int T = sT, cge = sCge;
  float* ob = out;                      // [B][150][4]
  float* osc = out + BATCH * MAXB * 4;  // [B][150]
  float* olb = out + BATCH * MAXB * 5;  // [B][150] labels (as float)
  if (cge <= SELCAP) {
    // fast path: compact bins >= T, exact rank-select the small set
    for (int i = tid; i < L; i += 1024) {
      u64 k = src[i];
      if ((int)(((u32)(k >> 32) - 0x3F666000u) >> 12) >= T) {
        int pos = atomicAdd(&nsel, 1);
        sel[pos] = k;
      }
    }
    __syncthreads();
    int C = nsel;
    for (int i = tid; i < C; i += 1024) {
      u64 k = sel[i];
      int rank = 0;
      for (int j = 0; j < C; ++j) rank += (sel[j] > k) ? 1 : 0;  // LDS broadcast
      if (rank < MAXB) slot[rank] = k;
    }
    __syncthreads();
  } else {
    // fallback (pathological concentration): exact rank-select over global list
    for (int i = tid; i < L; i += 1024) {
      u64 k = src[i];
      int rank = 0;
      for (int j = 0; j < L; ++j) rank += (src[j] > k) ? 1 : 0;
      if (rank < MAXB) slot[rank] = k;
    }
    __syncthreads();
  }
  if (tid < MAXB) {
    u64 k = slot[tid];
    float* q = ob + ((size_t)b * MAXB + tid) * 4;
    if (k) {
      u32 e = 0x3FFFu - (u32)((k >> 15) & 0x3FFFu);
      int c = (int)(e / MAXB);
      int anchor = (int)(k & 0x7FFFu);
      float4 bx = reinterpret_cast<const float4*>(boxes_ws)[(size_t)b * NANCH + anchor];
      q[0] = bx.x; q[1] = bx.y; q[2] = bx.z; q[3] = bx.w;
      osc[(size_t)b * MAXB + tid] = __uint_as_float((u32)(k >> 32));
      olb[(size_t)b * MAXB + tid] = (float)c;
    } else {
      q[0] = q[1] = q[2] = q[3] = -1.f;
      osc[(size_t)b * MAXB + tid] = -1.f;
      olb[(size_t)b * MAXB + tid] = -1.f;
    }
  }
}

extern "C" void kernel_launch(void* const* d_in, const int* in_sizes, int n_in,
                              void* d_out, int out_size, void* d_ws, size_t ws_size,
                              hipStream_t stream) {
  (void)in_sizes; (void)n_in; (void)out_size; (void)ws_size;
  const float* p0 = (const float*)d_in[0];  // [16,20,20,255] anchors[6:9]
  const float* p1 = (const float*)d_in[1];  // [16,40,40,255] anchors[3:6]
  const float* p2 = (const float*)d_in[2];  // [16,80,80,255] anchors[0:3]
  char* ws = (char*)d_ws;
  float* boxes_ws = (float*)ws;              // 16*25200*16 B          -> 6,451,200
  int* cand_cnt = (int*)(ws + 6451200);      // 1280*16 i32 (padded)   -> 6,533,120
  int* img_cnt = (int*)(ws + 6533120);       // 16*16 i32 (padded)     -> 6,534,144
  float* cs_arr = (float*)(ws + 6534144);    // 403200 f32             -> 8,146,944
  u64* cand_keys = (u64*)(ws + 8146944);     // 1280*2048 u64          -> 29,118,464
  u64* img_keys = (u64*)(ws + 29118464);     // 16*12000 u64           -> 30,654,464

  hipMemsetAsync(cand_cnt, 0, (NCLS * BATCH + BATCH) * CPAD * sizeof(int), stream);

  header_kernel<<<NREC_ALL / 256, 256, 0, stream>>>(p0, p1, p2, boxes_ws, cs_arr);
  scan_kernel<<<(NF4_ALL + 256 * SCAN_PER - 1) / (256 * SCAN_PER), 256, 0, stream>>>(
      p0, p1, p2, cs_arr, cand_keys, cand_cnt);
  nms_kernel<<<BATCH * NCLS, 256, 0, stream>>>(cand_keys, cand_cnt, boxes_ws,
                                               img_keys, img_cnt);
  final_kernel<<<BATCH, 1024, 0, stream>>>(img_keys, img_cnt, boxes_ws, (float*)d_out);
}